// Round 1
// baseline (217.574 us; speedup 1.0000x reference)
//
#include <hip/hip_runtime.h>
#include <math.h>

#define SCALE_MIN 0.5f
#define SCALE_MAX 15.0f
#define MULTIPLIER 0.1f
#define EPS 1e-8f

// native vector types (class-type float4 is rejected by nontemporal builtins)
typedef float v4f __attribute__((ext_vector_type(4)));
typedef float v2f __attribute__((ext_vector_type(2)));

// Output layout (flat concat, f32):
//   means      [BN*3]  @ 0
//   cov        [BN*9]  @ 3*BN
//   harmonics  [BN*12] @ 12*BN
//   opacities  [BN*1]  @ 24*BN
//   scales     [BN*3]  @ 25*BN
//   rotations  [BN*4]  @ 28*BN
//
// Wave-private staging version: each 64-lane wave stages ONLY its own 64
// gaussians in its private LDS slice. Same-wave DS ops are processed
// in order, so NO __syncthreads is needed anywhere — waves drift freely,
// keeping the memory pipe continuously fed instead of lockstepping 8
// waves at block barriers.
//
// Input staging uses global_load_lds (dest = uniform base + lane*16B,
// which is exactly our linear layout) — no VGPR round-trip.
// Output staging reuses the same wave slice in two phases, both smaller
// than the 1216-float input slice, so LDS/block = 4*1216*4 = 19456 B
// (8 blocks/CU by LDS; __launch_bounds__(256,8) targets 64 VGPR so
// occupancy is 32 waves/CU).

#define WVF 1216      // floats per wave slice (64 gaussians * 19)
// phase-A offsets within wave slice (floats)
#define A_MEAN  0     // 192 floats
#define A_COV   192   // 576 floats
#define A_SCALE 768   // 192 floats  (ends at 960 <= 1216)
// phase-B: harmonics at offset 0 (768 floats)

__global__ __launch_bounds__(256, 8) void mono_gaussian_adapter_kernel(
    const float* __restrict__ ext,    // B*16 (B,1,4,4)
    const float* __restrict__ intr,   // B*9  (B,1,3,3)
    const float* __restrict__ coord,  // BN*2
    const float* __restrict__ depth,  // BN
    const float* __restrict__ opac,   // BN
    const float* __restrict__ rawg,   // BN*19
    const int* __restrict__ hp,
    const int* __restrict__ wp,
    float* __restrict__ out,
    int bpb,                          // blocks per batch (N/256)
    int BN)
{
    __shared__ __align__(16) float lds[4 * WVF];

    const int tid  = threadIdx.x;
    const int lane = tid & 63;
    const int wid  = tid >> 6;
    const int blk  = blockIdx.x;
    const int gid  = blk * 256 + tid;        // this thread's gaussian
    const int gw   = blk * 4 + wid;          // global wave index (64 gaussians)
    const int b    = blk / bpb;              // block-uniform -> scalar path

    float* lw = lds + wid * WVF;             // wave-private LDS slice

    // ---- async LDS-DMA: this wave's 64x19 floats = 304 v4f ----
    // dest is uniform base + lane*16 (hardware), source is per-lane.
    {
        const v4f* gsrc = (const v4f*)(rawg + (long long)gw * (64 * 19));
        #pragma unroll
        for (int i = 0; i < 4; ++i) {
            __builtin_amdgcn_global_load_lds(
                (const __attribute__((address_space(1))) void*)(gsrc + i * 64 + lane),
                (__attribute__((address_space(3))) void*)((v4f*)lw + i * 64),
                16, 0, 0);
        }
        if (lane < 48) {   // tail: 304 - 256 = 48 v4f
            __builtin_amdgcn_global_load_lds(
                (const __attribute__((address_space(1))) void*)(gsrc + 256 + lane),
                (__attribute__((address_space(3))) void*)((v4f*)lw + 256),
                16, 0, 0);
        }
    }

    // ---- per-gaussian coalesced direct NT loads (overlap with DMA) ----
    v2f uv  = __builtin_nontemporal_load((const v2f*)coord + gid);
    float dep = __builtin_nontemporal_load(depth + gid);
    float op  = __builtin_nontemporal_load(opac + gid);

    float inv_w = 1.0f / (float)wp[0];
    float inv_h = 1.0f / (float)hp[0];

    // ---- per-batch (block-uniform) constants — SGPR path ----
    const float* E = ext + b * 16;
    float c00=E[0],  c01=E[1],  c02=E[2],  t0=E[3];
    float c10=E[4],  c11=E[5],  c12=E[6],  t1=E[7];
    float c20=E[8],  c21=E[9],  c22=E[10], t2=E[11];

    const float* Kb = intr + b * 9;
    float k00=Kb[0],k01=Kb[1],k02=Kb[2];
    float k10=Kb[3],k11=Kb[4],k12=Kb[5];
    float k20=Kb[6],k21=Kb[7],k22=Kb[8];

    float det2 = k00*k11 - k01*k10;
    float mult = MULTIPLIER * ((k11*inv_w - k01*inv_h) + (k00*inv_h - k10*inv_w)) / det2;

    float det3 = k00*(k11*k22 - k12*k21)
               + k01*(k12*k20 - k10*k22)
               + k02*(k10*k21 - k11*k20);
    float id3 = 1.0f / det3;
    float i00 = (k11*k22 - k12*k21)*id3;
    float i01 = (k02*k21 - k01*k22)*id3;
    float i02 = (k01*k12 - k02*k11)*id3;
    float i10 = (k12*k20 - k10*k22)*id3;
    float i11 = (k00*k22 - k02*k20)*id3;
    float i12 = (k02*k10 - k00*k12)*id3;
    float i20 = (k10*k21 - k11*k20)*id3;
    float i21 = (k01*k20 - k00*k21)*id3;
    float i22 = (k00*k11 - k01*k10)*id3;

    // ---- wait for this wave's own LDS-DMA (per-wave counter, no barrier) ----
    asm volatile("s_waitcnt vmcnt(0)" ::: "memory");

    // ---- per-lane fragment from LDS (stride 19 = odd -> conflict-free) ----
    const float* g = lw + lane * 19;
    float sr0 = g[0], sr1 = g[1], sr2 = g[2];
    float q0 = g[3], q1 = g[4], q2 = g[5], q3 = g[6];
    float sh00=g[7],  sh01=g[8],  sh02=g[9],  sh03=g[10];
    float sh10=g[11], sh11=g[12], sh12=g[13], sh13=g[14];
    float sh20=g[15], sh21=g[16], sh22=g[17], sh23=g[18];

    // ---- scales ----
    float s0 = SCALE_MIN + (SCALE_MAX - SCALE_MIN) / (1.0f + __expf(-sr0));
    float s1 = SCALE_MIN + (SCALE_MAX - SCALE_MIN) / (1.0f + __expf(-sr1));
    float s2 = SCALE_MIN + (SCALE_MAX - SCALE_MIN) / (1.0f + __expf(-sr2));
    float dm = dep * mult;
    s0 *= dm; s1 *= dm; s2 *= dm;

    // ---- rotations (normalized quat, order w,x,y,z) ----
    float qn = sqrtf(q0*q0 + q1*q1 + q2*q2 + q3*q3) + EPS;
    float qi = 1.0f / qn;
    float qw = q0*qi, qx = q1*qi, qy = q2*qi, qz = q3*qi;

    // direct NT stores for already-coalesced sections (free regs early)
    __builtin_nontemporal_store(op, out + 24LL*BN + gid);
    v4f rq = { qw, qx, qy, qz };
    __builtin_nontemporal_store(rq, (v4f*)(out + 28LL*BN) + gid);

    float r00 = 1.0f - 2.0f*(qy*qy + qz*qz);
    float r01 = 2.0f*(qx*qy - qw*qz);
    float r02 = 2.0f*(qx*qz + qw*qy);
    float r10 = 2.0f*(qx*qy + qw*qz);
    float r11 = 1.0f - 2.0f*(qx*qx + qz*qz);
    float r12 = 2.0f*(qy*qz - qw*qx);
    float r20 = 2.0f*(qx*qz - qw*qy);
    float r21 = 2.0f*(qy*qz + qw*qx);
    float r22 = 1.0f - 2.0f*(qx*qx + qy*qy);

    // ---- cov0 = R diag(s^2) R^T, then c2w conjugation ----
    float v0 = s0*s0, v1 = s1*s1, v2 = s2*s2;
    float p00 = r00*r00*v0 + r01*r01*v1 + r02*r02*v2;
    float p01 = r00*r10*v0 + r01*r11*v1 + r02*r12*v2;
    float p02 = r00*r20*v0 + r01*r21*v1 + r02*r22*v2;
    float p11 = r10*r10*v0 + r11*r11*v1 + r12*r12*v2;
    float p12 = r10*r20*v0 + r11*r21*v1 + r12*r22*v2;
    float p22 = r20*r20*v0 + r21*r21*v1 + r22*r22*v2;

    float m00 = c00*p00 + c01*p01 + c02*p02;
    float m01 = c00*p01 + c01*p11 + c02*p12;
    float m02 = c00*p02 + c01*p12 + c02*p22;
    float m10 = c10*p00 + c11*p01 + c12*p02;
    float m11 = c10*p01 + c11*p11 + c12*p12;
    float m12 = c10*p02 + c11*p12 + c12*p22;
    float m20 = c20*p00 + c21*p01 + c22*p02;
    float m21 = c20*p01 + c21*p11 + c22*p12;
    float m22 = c20*p02 + c21*p12 + c22*p22;

    float q00 = m00*c00 + m01*c01 + m02*c02;
    float q01 = m00*c10 + m01*c11 + m02*c12;
    float q02 = m00*c20 + m01*c21 + m02*c22;
    float q11 = m10*c10 + m11*c11 + m12*c12;
    float q12 = m10*c20 + m11*c21 + m12*c22;
    float q22 = m20*c20 + m21*c21 + m22*c22;

    // ---- means ----
    float d0 = i00*uv.x + i01*uv.y + i02;
    float d1 = i10*uv.x + i11*uv.y + i12;
    float d2 = i20*uv.x + i21*uv.y + i22;
    float rn = rsqrtf(d0*d0 + d1*d1 + d2*d2);
    d0 *= rn; d1 *= rn; d2 *= rn;
    float w0 = c00*d0 + c01*d1 + c02*d2;
    float w1 = c10*d0 + c11*d1 + c12*d2;
    float w2 = c20*d0 + c21*d1 + c22*d2;
    float me0 = t0 + w0*dep;
    float me1 = t1 + w1*dep;
    float me2 = t2 + w2*dep;

    // ---- harmonics: [sh0 | D1 @ (0.025*sh1)]; D1[i][j]=c2w[p[i]][p[j]], p=[1,2,0]
    float D00=c11, D01=c12, D02=c10;
    float D10=c21, D11=c22, D12=c20;
    float D20=c01, D21=c02, D22=c00;
    const float msk = 0.1f * 0.25f;
    float a1 = msk*sh01, a2 = msk*sh02, a3 = msk*sh03;
    float b1 = msk*sh11, b2 = msk*sh12, b3 = msk*sh13;
    float e1 = msk*sh21, e2 = msk*sh22, e3 = msk*sh23;
    v4f h0 = { sh00, D00*a1 + D01*a2 + D02*a3,
                     D10*a1 + D11*a2 + D12*a3,
                     D20*a1 + D21*a2 + D22*a3 };
    v4f h1 = { sh10, D00*b1 + D01*b2 + D02*b3,
                     D10*b1 + D11*b2 + D12*b3,
                     D20*b1 + D21*b2 + D22*b3 };
    v4f h2 = { sh20, D00*e1 + D01*e2 + D02*e3,
                     D10*e1 + D11*e2 + D12*e3,
                     D20*e1 + D21*e2 + D22*e3 };

    // ================= phase A: means + cov + scales =================
    // stage (odd strides 3/9 -> conflict-free); wave-private, no barrier:
    // same-wave DS ops execute in order, so WAR vs the fragment reads is safe.
    {
        float* lm = lw + A_MEAN + lane * 3;
        lm[0] = me0; lm[1] = me1; lm[2] = me2;

        float* lc = lw + A_COV + lane * 9;
        lc[0]=q00; lc[1]=q01; lc[2]=q02;
        lc[3]=q01; lc[4]=q11; lc[5]=q12;
        lc[6]=q02; lc[7]=q12; lc[8]=q22;

        float* ls = lw + A_SCALE + lane * 3;
        ls[0] = s0; ls[1] = s1; ls[2] = s2;
    }
    // lane-contiguous 16B NT writeback of this wave's slice
    {
        const v4f* l4 = (const v4f*)lw;
        v4f* gm = (v4f*)(out + (long long)gw * 192);              // means
        v4f* gs = (v4f*)(out + 25LL*BN + (long long)gw * 192);    // scales
        if (lane < 48) {
            __builtin_nontemporal_store(l4[(A_MEAN / 4) + lane], gm + lane);
            __builtin_nontemporal_store(l4[(A_SCALE / 4) + lane], gs + lane);
        }
        v4f* gc = (v4f*)(out + 3LL*BN + (long long)gw * 576);     // cov: 144 v4f
        #pragma unroll
        for (int i = 0; i < 2; ++i)
            __builtin_nontemporal_store(l4[(A_COV / 4) + lane + i*64], gc + lane + i*64);
        if (lane < 16)
            __builtin_nontemporal_store(l4[(A_COV / 4) + lane + 128], gc + lane + 128);
    }

    // ================= phase B: harmonics =================
    // WAR vs phase-A LDS reads is safe (in-order same-wave DS pipeline).
    {
        v4f* lh = (v4f*)lw + lane * 3;    // 48B stride: 8 words/bank = full rate
        lh[0] = h0; lh[1] = h1; lh[2] = h2;
    }
    {
        const v4f* l4 = (const v4f*)lw;
        v4f* gh = (v4f*)(out + 12LL*BN + (long long)gw * 768);    // 192 v4f
        #pragma unroll
        for (int i = 0; i < 3; ++i)
            __builtin_nontemporal_store(l4[lane + i*64], gh + lane + i*64);
    }
}

extern "C" void kernel_launch(void* const* d_in, const int* in_sizes, int n_in,
                              void* d_out, int out_size, void* d_ws, size_t ws_size,
                              hipStream_t stream) {
    const float* ext   = (const float*)d_in[0];
    const float* intr  = (const float*)d_in[1];
    const float* coord = (const float*)d_in[2];
    const float* depth = (const float*)d_in[3];
    const float* opac  = (const float*)d_in[4];
    const float* rawg  = (const float*)d_in[5];
    const int*   hp    = (const int*)d_in[6];
    const int*   wp    = (const int*)d_in[7];

    int BN = in_sizes[3];            // B*N (1048576 here, % 256 == 0)
    int B  = in_sizes[0] / 16;       // extrinsics: B*1*4*4
    int N  = BN / B;
    int blocks = BN / 256;           // BN % 256 == 0
    int bpb = N / 256;               // blocks per batch

    mono_gaussian_adapter_kernel<<<blocks, 256, 0, stream>>>(
        ext, intr, coord, depth, opac, rawg, hp, wp,
        (float*)d_out, bpb, BN);
}

// Round 2
// 216.812 us; speedup vs baseline: 1.0035x; 1.0035x over previous
//
#include <hip/hip_runtime.h>
#include <math.h>

#define SCALE_MIN 0.5f
#define SCALE_MAX 15.0f
#define MULTIPLIER 0.1f
#define EPS 1e-8f

// native vector types (class-type float4 is rejected by nontemporal builtins)
typedef float v4f __attribute__((ext_vector_type(4)));
typedef float v2f __attribute__((ext_vector_type(2)));

// Output layout (flat concat, f32):
//   means      [BN*3]  @ 0
//   cov        [BN*9]  @ 3*BN
//   harmonics  [BN*12] @ 12*BN
//   opacities  [BN*1]  @ 24*BN
//   scales     [BN*3]  @ 25*BN
//   rotations  [BN*4]  @ 28*BN
//
// Wave-private staging: each 64-lane wave stages ONLY its own 64 gaussians
// in its private LDS slice. Same-wave DS ops are processed in order, so NO
// __syncthreads is needed anywhere — waves drift freely.
//
// Input staging uses global_load_lds (dest = uniform base + lane*16B).
// Output staging reuses the same wave slice in two phases, both smaller
// than the 1216-float input slice, so LDS/block = 4*1216*4 = 19456 B.
//
// __launch_bounds__(256, 4): 128-VGPR ceiling. Round-1 used (256,8) which
// caps VGPR at 64 — the ~90-float peak live set (c2w + Kinv + sh + R + cov
// temps + harmonics) spilled to scratch, adding ~100 MB of spill traffic on
// a 230 MB-essential streaming kernel (measured ~+10us kernel slice).
// (256,4) fits the live set with margin; >=16 waves/CU is ample TLP for
// a pure streaming kernel.

#define WVF 1216      // floats per wave slice (64 gaussians * 19)
// phase-A offsets within wave slice (floats)
#define A_MEAN  0     // 192 floats
#define A_COV   192   // 576 floats
#define A_SCALE 768   // 192 floats  (ends at 960 <= 1216)
// phase-B: harmonics at offset 0 (768 floats)

__global__ __launch_bounds__(256, 4) void mono_gaussian_adapter_kernel(
    const float* __restrict__ ext,    // B*16 (B,1,4,4)
    const float* __restrict__ intr,   // B*9  (B,1,3,3)
    const float* __restrict__ coord,  // BN*2
    const float* __restrict__ depth,  // BN
    const float* __restrict__ opac,   // BN
    const float* __restrict__ rawg,   // BN*19
    const int* __restrict__ hp,
    const int* __restrict__ wp,
    float* __restrict__ out,
    int bpb,                          // blocks per batch (N/256)
    int BN)
{
    __shared__ __align__(16) float lds[4 * WVF];

    const int tid  = threadIdx.x;
    const int lane = tid & 63;
    const int wid  = tid >> 6;
    const int blk  = blockIdx.x;
    const int gid  = blk * 256 + tid;        // this thread's gaussian
    const int gw   = blk * 4 + wid;          // global wave index (64 gaussians)
    const int b    = blk / bpb;              // block-uniform -> scalar path

    float* lw = lds + wid * WVF;             // wave-private LDS slice

    // ---- async LDS-DMA: this wave's 64x19 floats = 304 v4f ----
    // dest is uniform base + lane*16 (hardware), source is per-lane.
    {
        const v4f* gsrc = (const v4f*)(rawg + (long long)gw * (64 * 19));
        #pragma unroll
        for (int i = 0; i < 4; ++i) {
            __builtin_amdgcn_global_load_lds(
                (const __attribute__((address_space(1))) void*)(gsrc + i * 64 + lane),
                (__attribute__((address_space(3))) void*)((v4f*)lw + i * 64),
                16, 0, 0);
        }
        if (lane < 48) {   // tail: 304 - 256 = 48 v4f
            __builtin_amdgcn_global_load_lds(
                (const __attribute__((address_space(1))) void*)(gsrc + 256 + lane),
                (__attribute__((address_space(3))) void*)((v4f*)lw + 256),
                16, 0, 0);
        }
    }

    // ---- per-gaussian coalesced direct NT loads (overlap with DMA) ----
    v2f uv  = __builtin_nontemporal_load((const v2f*)coord + gid);
    float dep = __builtin_nontemporal_load(depth + gid);
    float op  = __builtin_nontemporal_load(opac + gid);

    float inv_w = 1.0f / (float)wp[0];
    float inv_h = 1.0f / (float)hp[0];

    // ---- per-batch (block-uniform) constants — SGPR path ----
    const float* E = ext + b * 16;
    float c00=E[0],  c01=E[1],  c02=E[2],  t0=E[3];
    float c10=E[4],  c11=E[5],  c12=E[6],  t1=E[7];
    float c20=E[8],  c21=E[9],  c22=E[10], t2=E[11];

    const float* Kb = intr + b * 9;
    float k00=Kb[0],k01=Kb[1],k02=Kb[2];
    float k10=Kb[3],k11=Kb[4],k12=Kb[5];
    float k20=Kb[6],k21=Kb[7],k22=Kb[8];

    float det2 = k00*k11 - k01*k10;
    float mult = MULTIPLIER * ((k11*inv_w - k01*inv_h) + (k00*inv_h - k10*inv_w)) / det2;

    float det3 = k00*(k11*k22 - k12*k21)
               + k01*(k12*k20 - k10*k22)
               + k02*(k10*k21 - k11*k20);
    float id3 = 1.0f / det3;
    float i00 = (k11*k22 - k12*k21)*id3;
    float i01 = (k02*k21 - k01*k22)*id3;
    float i02 = (k01*k12 - k02*k11)*id3;
    float i10 = (k12*k20 - k10*k22)*id3;
    float i11 = (k00*k22 - k02*k20)*id3;
    float i12 = (k02*k10 - k00*k12)*id3;
    float i20 = (k10*k21 - k11*k20)*id3;
    float i21 = (k01*k20 - k00*k21)*id3;
    float i22 = (k00*k11 - k01*k10)*id3;

    // ---- wait for this wave's own LDS-DMA (per-wave counter, no barrier) ----
    asm volatile("s_waitcnt vmcnt(0)" ::: "memory");

    // ---- per-lane fragment from LDS (stride 19 = odd -> conflict-free) ----
    const float* g = lw + lane * 19;
    float sr0 = g[0], sr1 = g[1], sr2 = g[2];
    float q0 = g[3], q1 = g[4], q2 = g[5], q3 = g[6];
    float sh00=g[7],  sh01=g[8],  sh02=g[9],  sh03=g[10];
    float sh10=g[11], sh11=g[12], sh12=g[13], sh13=g[14];
    float sh20=g[15], sh21=g[16], sh22=g[17], sh23=g[18];

    // ---- scales ----
    float s0 = SCALE_MIN + (SCALE_MAX - SCALE_MIN) / (1.0f + __expf(-sr0));
    float s1 = SCALE_MIN + (SCALE_MAX - SCALE_MIN) / (1.0f + __expf(-sr1));
    float s2 = SCALE_MIN + (SCALE_MAX - SCALE_MIN) / (1.0f + __expf(-sr2));
    float dm = dep * mult;
    s0 *= dm; s1 *= dm; s2 *= dm;

    // ---- rotations (normalized quat, order w,x,y,z) ----
    float qn = sqrtf(q0*q0 + q1*q1 + q2*q2 + q3*q3) + EPS;
    float qi = 1.0f / qn;
    float qw = q0*qi, qx = q1*qi, qy = q2*qi, qz = q3*qi;

    // direct NT stores for already-coalesced sections (free regs early)
    __builtin_nontemporal_store(op, out + 24LL*BN + gid);
    v4f rq = { qw, qx, qy, qz };
    __builtin_nontemporal_store(rq, (v4f*)(out + 28LL*BN) + gid);

    float r00 = 1.0f - 2.0f*(qy*qy + qz*qz);
    float r01 = 2.0f*(qx*qy - qw*qz);
    float r02 = 2.0f*(qx*qz + qw*qy);
    float r10 = 2.0f*(qx*qy + qw*qz);
    float r11 = 1.0f - 2.0f*(qx*qx + qz*qz);
    float r12 = 2.0f*(qy*qz - qw*qx);
    float r20 = 2.0f*(qx*qz - qw*qy);
    float r21 = 2.0f*(qy*qz + qw*qx);
    float r22 = 1.0f - 2.0f*(qx*qx + qy*qy);

    // ---- cov0 = R diag(s^2) R^T, then c2w conjugation ----
    float v0 = s0*s0, v1 = s1*s1, v2 = s2*s2;
    float p00 = r00*r00*v0 + r01*r01*v1 + r02*r02*v2;
    float p01 = r00*r10*v0 + r01*r11*v1 + r02*r12*v2;
    float p02 = r00*r20*v0 + r01*r21*v1 + r02*r22*v2;
    float p11 = r10*r10*v0 + r11*r11*v1 + r12*r12*v2;
    float p12 = r10*r20*v0 + r11*r21*v1 + r12*r22*v2;
    float p22 = r20*r20*v0 + r21*r21*v1 + r22*r22*v2;

    float m00 = c00*p00 + c01*p01 + c02*p02;
    float m01 = c00*p01 + c01*p11 + c02*p12;
    float m02 = c00*p02 + c01*p12 + c02*p22;
    float m10 = c10*p00 + c11*p01 + c12*p02;
    float m11 = c10*p01 + c11*p11 + c12*p12;
    float m12 = c10*p02 + c11*p12 + c12*p22;
    float m20 = c20*p00 + c21*p01 + c22*p02;
    float m21 = c20*p01 + c21*p11 + c22*p12;
    float m22 = c20*p02 + c21*p12 + c22*p22;

    float q00 = m00*c00 + m01*c01 + m02*c02;
    float q01 = m00*c10 + m01*c11 + m02*c12;
    float q02 = m00*c20 + m01*c21 + m02*c22;
    float q11 = m10*c10 + m11*c11 + m12*c12;
    float q12 = m10*c20 + m11*c21 + m12*c22;
    float q22 = m20*c20 + m21*c21 + m22*c22;

    // ---- means ----
    float d0 = i00*uv.x + i01*uv.y + i02;
    float d1 = i10*uv.x + i11*uv.y + i12;
    float d2 = i20*uv.x + i21*uv.y + i22;
    float rn = rsqrtf(d0*d0 + d1*d1 + d2*d2);
    d0 *= rn; d1 *= rn; d2 *= rn;
    float w0 = c00*d0 + c01*d1 + c02*d2;
    float w1 = c10*d0 + c11*d1 + c12*d2;
    float w2 = c20*d0 + c21*d1 + c22*d2;
    float me0 = t0 + w0*dep;
    float me1 = t1 + w1*dep;
    float me2 = t2 + w2*dep;

    // ---- harmonics: [sh0 | D1 @ (0.025*sh1)]; D1[i][j]=c2w[p[i]][p[j]], p=[1,2,0]
    float D00=c11, D01=c12, D02=c10;
    float D10=c21, D11=c22, D12=c20;
    float D20=c01, D21=c02, D22=c00;
    const float msk = 0.1f * 0.25f;
    float a1 = msk*sh01, a2 = msk*sh02, a3 = msk*sh03;
    float b1 = msk*sh11, b2 = msk*sh12, b3 = msk*sh13;
    float e1 = msk*sh21, e2 = msk*sh22, e3 = msk*sh23;
    v4f h0 = { sh00, D00*a1 + D01*a2 + D02*a3,
                     D10*a1 + D11*a2 + D12*a3,
                     D20*a1 + D21*a2 + D22*a3 };
    v4f h1 = { sh10, D00*b1 + D01*b2 + D02*b3,
                     D10*b1 + D11*b2 + D12*b3,
                     D20*b1 + D21*b2 + D22*b3 };
    v4f h2 = { sh20, D00*e1 + D01*e2 + D02*e3,
                     D10*e1 + D11*e2 + D12*e3,
                     D20*e1 + D21*e2 + D22*e3 };

    // ================= phase A: means + cov + scales =================
    // stage (odd strides 3/9 -> conflict-free); wave-private, no barrier:
    // same-wave DS ops execute in order, so WAR vs the fragment reads is safe.
    {
        float* lm = lw + A_MEAN + lane * 3;
        lm[0] = me0; lm[1] = me1; lm[2] = me2;

        float* lc = lw + A_COV + lane * 9;
        lc[0]=q00; lc[1]=q01; lc[2]=q02;
        lc[3]=q01; lc[4]=q11; lc[5]=q12;
        lc[6]=q02; lc[7]=q12; lc[8]=q22;

        float* ls = lw + A_SCALE + lane * 3;
        ls[0] = s0; ls[1] = s1; ls[2] = s2;
    }
    // lane-contiguous 16B NT writeback of this wave's slice
    {
        const v4f* l4 = (const v4f*)lw;
        v4f* gm = (v4f*)(out + (long long)gw * 192);              // means
        v4f* gs = (v4f*)(out + 25LL*BN + (long long)gw * 192);    // scales
        if (lane < 48) {
            __builtin_nontemporal_store(l4[(A_MEAN / 4) + lane], gm + lane);
            __builtin_nontemporal_store(l4[(A_SCALE / 4) + lane], gs + lane);
        }
        v4f* gc = (v4f*)(out + 3LL*BN + (long long)gw * 576);     // cov: 144 v4f
        #pragma unroll
        for (int i = 0; i < 2; ++i)
            __builtin_nontemporal_store(l4[(A_COV / 4) + lane + i*64], gc + lane + i*64);
        if (lane < 16)
            __builtin_nontemporal_store(l4[(A_COV / 4) + lane + 128], gc + lane + 128);
    }

    // ================= phase B: harmonics =================
    // WAR vs phase-A LDS reads is safe (in-order same-wave DS pipeline).
    {
        v4f* lh = (v4f*)lw + lane * 3;    // 48B stride: uniform 8 touches/bank
        lh[0] = h0; lh[1] = h1; lh[2] = h2;
    }
    {
        const v4f* l4 = (const v4f*)lw;
        v4f* gh = (v4f*)(out + 12LL*BN + (long long)gw * 768);    // 192 v4f
        #pragma unroll
        for (int i = 0; i < 3; ++i)
            __builtin_nontemporal_store(l4[lane + i*64], gh + lane + i*64);
    }
}

extern "C" void kernel_launch(void* const* d_in, const int* in_sizes, int n_in,
                              void* d_out, int out_size, void* d_ws, size_t ws_size,
                              hipStream_t stream) {
    const float* ext   = (const float*)d_in[0];
    const float* intr  = (const float*)d_in[1];
    const float* coord = (const float*)d_in[2];
    const float* depth = (const float*)d_in[3];
    const float* opac  = (const float*)d_in[4];
    const float* rawg  = (const float*)d_in[5];
    const int*   hp    = (const int*)d_in[6];
    const int*   wp    = (const int*)d_in[7];

    int BN = in_sizes[3];            // B*N (1048576 here, % 256 == 0)
    int B  = in_sizes[0] / 16;       // extrinsics: B*1*4*4
    int N  = BN / B;
    int blocks = BN / 256;           // BN % 256 == 0
    int bpb = N / 256;               // blocks per batch

    mono_gaussian_adapter_kernel<<<blocks, 256, 0, stream>>>(
        ext, intr, coord, depth, opac, rawg, hp, wp,
        (float*)d_out, bpb, BN);
}

// Round 3
// 212.586 us; speedup vs baseline: 1.0235x; 1.0199x over previous
//
#include <hip/hip_runtime.h>
#include <math.h>

#define SCALE_MIN 0.5f
#define SCALE_MAX 15.0f
#define MULTIPLIER 0.1f
#define EPS 1e-8f

// native vector types (class-type float4 is rejected by nontemporal builtins)
typedef float v4f __attribute__((ext_vector_type(4)));
typedef float v2f __attribute__((ext_vector_type(2)));

// Output layout (flat concat, f32):
//   means      [BN*3]  @ 0
//   cov        [BN*9]  @ 3*BN
//   harmonics  [BN*12] @ 12*BN
//   opacities  [BN*1]  @ 24*BN
//   scales     [BN*3]  @ 25*BN
//   rotations  [BN*4]  @ 28*BN
//
// ROUND-0 DATA PATH + WAVE-PRIVATE LDS (no barriers):
//  - rawg staged via NT vector loads into VGPRs then ds_write (NOT
//    global_load_lds: the hand-written full-drain vmcnt(0) that DMA
//    requires defeated the compiler's precise per-load vmcnt(N)
//    interleave and cost ~10us kernel-slice in rounds 1-2).
//  - each wave owns a private 1728-float LDS slice for its 64 gaussians;
//    same-wave DS ops are in-order wave-wide, so ZERO __syncthreads:
//    waves drift freely instead of lockstepping at 3 block barriers.
//  - LDS/block = 4*1728*4 = 27648 B (same as round 0; occupancy limited
//    by waves at 4 blocks/CU either way).
//  - no min-waves launch bound: let the allocator use what it needs
//    (round-1's 64-VGPR cap spilled).

#define WVF 1728      // floats per wave slice: max(input 19*64=1216, output 27*64=1728)
// output-phase offsets within wave slice (floats)
#define O_MEAN  0     // 192
#define O_COV   192   // 576
#define O_HARM  768   // 768
#define O_SCALE 1536  // 192  (total 1728)

__global__ __launch_bounds__(256) void mono_gaussian_adapter_kernel(
    const float* __restrict__ ext,    // B*16 (B,1,4,4)
    const float* __restrict__ intr,   // B*9  (B,1,3,3)
    const float* __restrict__ coord,  // BN*2
    const float* __restrict__ depth,  // BN
    const float* __restrict__ opac,   // BN
    const float* __restrict__ rawg,   // BN*19
    const int* __restrict__ hp,
    const int* __restrict__ wp,
    float* __restrict__ out,
    int bpb,                          // blocks per batch (N/256)
    int BN)
{
    __shared__ __align__(16) float lds[4 * WVF];

    const int tid  = threadIdx.x;
    const int lane = tid & 63;
    const int wid  = tid >> 6;
    const int blk  = blockIdx.x;
    const int gid  = blk * 256 + tid;        // this thread's gaussian
    const int gw   = blk * 4 + wid;          // global wave index (64 gaussians)
    const int b    = blk / bpb;              // block-uniform -> scalar path

    float* lw = lds + wid * WVF;             // wave-private LDS slice

    // ---- NT vector loads of this wave's rawg block (304 v4f) into VGPRs ----
    const v4f* gin = (const v4f*)(rawg + (long long)gw * (64 * 19));
    v4f s0v = __builtin_nontemporal_load(gin + lane);
    v4f s1v = __builtin_nontemporal_load(gin + 64 + lane);
    v4f s2v = __builtin_nontemporal_load(gin + 128 + lane);
    v4f s3v = __builtin_nontemporal_load(gin + 192 + lane);
    v4f s4v;
    if (lane < 48) s4v = __builtin_nontemporal_load(gin + 256 + lane);

    // ---- per-gaussian coalesced direct NT loads (overlap with staging) ----
    v2f uv  = __builtin_nontemporal_load((const v2f*)coord + gid);
    float dep = __builtin_nontemporal_load(depth + gid);
    float op  = __builtin_nontemporal_load(opac + gid);

    float inv_w = 1.0f / (float)wp[0];
    float inv_h = 1.0f / (float)hp[0];

    // ---- per-batch (block-uniform) constants — scalar path ----
    const float* E = ext + b * 16;
    float c00=E[0],  c01=E[1],  c02=E[2],  t0=E[3];
    float c10=E[4],  c11=E[5],  c12=E[6],  t1=E[7];
    float c20=E[8],  c21=E[9],  c22=E[10], t2=E[11];

    const float* Kb = intr + b * 9;
    float k00=Kb[0],k01=Kb[1],k02=Kb[2];
    float k10=Kb[3],k11=Kb[4],k12=Kb[5];
    float k20=Kb[6],k21=Kb[7],k22=Kb[8];

    float det2 = k00*k11 - k01*k10;
    float mult = MULTIPLIER * ((k11*inv_w - k01*inv_h) + (k00*inv_h - k10*inv_w)) / det2;

    float det3 = k00*(k11*k22 - k12*k21)
               + k01*(k12*k20 - k10*k22)
               + k02*(k10*k21 - k11*k20);
    float id3 = 1.0f / det3;
    float i00 = (k11*k22 - k12*k21)*id3;
    float i01 = (k02*k21 - k01*k22)*id3;
    float i02 = (k01*k12 - k02*k11)*id3;
    float i10 = (k12*k20 - k10*k22)*id3;
    float i11 = (k00*k22 - k02*k20)*id3;
    float i12 = (k02*k10 - k00*k12)*id3;
    float i20 = (k10*k21 - k11*k20)*id3;
    float i21 = (k01*k20 - k00*k21)*id3;
    float i22 = (k00*k11 - k01*k10)*id3;

    // ---- ds_write staging (compiler inserts precise vmcnt(N) waits) ----
    {
        v4f* l4 = (v4f*)lw;
        l4[lane]       = s0v;
        l4[64 + lane]  = s1v;
        l4[128 + lane] = s2v;
        l4[192 + lane] = s3v;
        if (lane < 48) l4[256 + lane] = s4v;
    }

    // ---- per-lane fragment from LDS (stride 19 = odd -> conflict-free) ----
    // Same-wave DS ops execute in order wave-wide: once the ds_writes above
    // retire (compiler lgkmcnt), all 64 lanes' data is visible. No barrier.
    const float* g = lw + lane * 19;
    float sr0 = g[0], sr1 = g[1], sr2 = g[2];
    float q0 = g[3], q1 = g[4], q2 = g[5], q3 = g[6];
    float sh00=g[7],  sh01=g[8],  sh02=g[9],  sh03=g[10];
    float sh10=g[11], sh11=g[12], sh12=g[13], sh13=g[14];
    float sh20=g[15], sh21=g[16], sh22=g[17], sh23=g[18];

    // ---- scales ----
    float s0 = SCALE_MIN + (SCALE_MAX - SCALE_MIN) / (1.0f + __expf(-sr0));
    float s1 = SCALE_MIN + (SCALE_MAX - SCALE_MIN) / (1.0f + __expf(-sr1));
    float s2 = SCALE_MIN + (SCALE_MAX - SCALE_MIN) / (1.0f + __expf(-sr2));
    float dm = dep * mult;
    s0 *= dm; s1 *= dm; s2 *= dm;

    // ---- rotations (normalized quat, order w,x,y,z) ----
    float qn = sqrtf(q0*q0 + q1*q1 + q2*q2 + q3*q3) + EPS;
    float qi = 1.0f / qn;
    float qw = q0*qi, qx = q1*qi, qy = q2*qi, qz = q3*qi;

    // direct NT stores for already-coalesced sections
    __builtin_nontemporal_store(op, out + 24LL*BN + gid);
    v4f rq = { qw, qx, qy, qz };
    __builtin_nontemporal_store(rq, (v4f*)(out + 28LL*BN) + gid);

    float r00 = 1.0f - 2.0f*(qy*qy + qz*qz);
    float r01 = 2.0f*(qx*qy - qw*qz);
    float r02 = 2.0f*(qx*qz + qw*qy);
    float r10 = 2.0f*(qx*qy + qw*qz);
    float r11 = 1.0f - 2.0f*(qx*qx + qz*qz);
    float r12 = 2.0f*(qy*qz - qw*qx);
    float r20 = 2.0f*(qx*qz - qw*qy);
    float r21 = 2.0f*(qy*qz + qw*qx);
    float r22 = 1.0f - 2.0f*(qx*qx + qy*qy);

    // ---- cov0 = R diag(s^2) R^T, then c2w conjugation ----
    float v0 = s0*s0, v1 = s1*s1, v2 = s2*s2;
    float p00 = r00*r00*v0 + r01*r01*v1 + r02*r02*v2;
    float p01 = r00*r10*v0 + r01*r11*v1 + r02*r12*v2;
    float p02 = r00*r20*v0 + r01*r21*v1 + r02*r22*v2;
    float p11 = r10*r10*v0 + r11*r11*v1 + r12*r12*v2;
    float p12 = r10*r20*v0 + r11*r21*v1 + r12*r22*v2;
    float p22 = r20*r20*v0 + r21*r21*v1 + r22*r22*v2;

    float m00 = c00*p00 + c01*p01 + c02*p02;
    float m01 = c00*p01 + c01*p11 + c02*p12;
    float m02 = c00*p02 + c01*p12 + c02*p22;
    float m10 = c10*p00 + c11*p01 + c12*p02;
    float m11 = c10*p01 + c11*p11 + c12*p12;
    float m12 = c10*p02 + c11*p12 + c12*p22;
    float m20 = c20*p00 + c21*p01 + c22*p02;
    float m21 = c20*p01 + c21*p11 + c22*p12;
    float m22 = c20*p02 + c21*p12 + c22*p22;

    float q00 = m00*c00 + m01*c01 + m02*c02;
    float q01 = m00*c10 + m01*c11 + m02*c12;
    float q02 = m00*c20 + m01*c21 + m02*c22;
    float q11 = m10*c10 + m11*c11 + m12*c12;
    float q12 = m10*c20 + m11*c21 + m12*c22;
    float q22 = m20*c20 + m21*c21 + m22*c22;

    // ---- means ----
    float d0 = i00*uv.x + i01*uv.y + i02;
    float d1 = i10*uv.x + i11*uv.y + i12;
    float d2 = i20*uv.x + i21*uv.y + i22;
    float rn = rsqrtf(d0*d0 + d1*d1 + d2*d2);
    d0 *= rn; d1 *= rn; d2 *= rn;
    float w0 = c00*d0 + c01*d1 + c02*d2;
    float w1 = c10*d0 + c11*d1 + c12*d2;
    float w2 = c20*d0 + c21*d1 + c22*d2;
    float me0 = t0 + w0*dep;
    float me1 = t1 + w1*dep;
    float me2 = t2 + w2*dep;

    // ---- harmonics: [sh0 | D1 @ (0.025*sh1)]; D1[i][j]=c2w[p[i]][p[j]], p=[1,2,0]
    float D00=c11, D01=c12, D02=c10;
    float D10=c21, D11=c22, D12=c20;
    float D20=c01, D21=c02, D22=c00;
    const float msk = 0.1f * 0.25f;
    float a1 = msk*sh01, a2 = msk*sh02, a3 = msk*sh03;
    float b1 = msk*sh11, b2 = msk*sh12, b3 = msk*sh13;
    float e1 = msk*sh21, e2 = msk*sh22, e3 = msk*sh23;
    v4f h0 = { sh00, D00*a1 + D01*a2 + D02*a3,
                     D10*a1 + D11*a2 + D12*a3,
                     D20*a1 + D21*a2 + D22*a3 };
    v4f h1 = { sh10, D00*b1 + D01*b2 + D02*b3,
                     D10*b1 + D11*b2 + D12*b3,
                     D20*b1 + D21*b2 + D22*b3 };
    v4f h2 = { sh20, D00*e1 + D01*e2 + D02*e3,
                     D10*e1 + D11*e2 + D12*e3,
                     D20*e1 + D21*e2 + D22*e3 };

    // ---- stage odd-stride outputs in the wave slice (no barrier:
    //      WAR vs the fragment reads is safe, same-wave in-order DS) ----
    {
        float* lm = lw + O_MEAN + lane * 3;      // stride 3 (odd) -> free
        lm[0] = me0; lm[1] = me1; lm[2] = me2;

        float* lc = lw + O_COV + lane * 9;       // stride 9 (odd) -> free
        lc[0]=q00; lc[1]=q01; lc[2]=q02;
        lc[3]=q01; lc[4]=q11; lc[5]=q12;
        lc[6]=q02; lc[7]=q12; lc[8]=q22;

        v4f* lh = (v4f*)(lds + (wid * WVF + O_HARM)) + lane * 3;  // 48B stride
        lh[0] = h0; lh[1] = h1; lh[2] = h2;

        float* ls = lw + O_SCALE + lane * 3;     // stride 3 (odd) -> free
        ls[0] = s0; ls[1] = s1; ls[2] = s2;
    }

    // ---- cooperative lane-contiguous 16B NT writeback of the wave slice ----
    {
        const v4f* l4 = (const v4f*)lw;
        v4f* gm = (v4f*)(out + (long long)gw * 192);              // means: 48 v4f
        v4f* gs = (v4f*)(out + 25LL*BN + (long long)gw * 192);    // scales: 48 v4f
        if (lane < 48) {
            __builtin_nontemporal_store(l4[(O_MEAN / 4) + lane], gm + lane);
            __builtin_nontemporal_store(l4[(O_SCALE / 4) + lane], gs + lane);
        }
        v4f* gc = (v4f*)(out + 3LL*BN + (long long)gw * 576);     // cov: 144 v4f
        #pragma unroll
        for (int i = 0; i < 2; ++i)
            __builtin_nontemporal_store(l4[(O_COV / 4) + lane + i*64], gc + lane + i*64);
        if (lane < 16)
            __builtin_nontemporal_store(l4[(O_COV / 4) + lane + 128], gc + lane + 128);

        v4f* gh = (v4f*)(out + 12LL*BN + (long long)gw * 768);    // harm: 192 v4f
        #pragma unroll
        for (int i = 0; i < 3; ++i)
            __builtin_nontemporal_store(l4[(O_HARM / 4) + lane + i*64], gh + lane + i*64);
    }
}

extern "C" void kernel_launch(void* const* d_in, const int* in_sizes, int n_in,
                              void* d_out, int out_size, void* d_ws, size_t ws_size,
                              hipStream_t stream) {
    const float* ext   = (const float*)d_in[0];
    const float* intr  = (const float*)d_in[1];
    const float* coord = (const float*)d_in[2];
    const float* depth = (const float*)d_in[3];
    const float* opac  = (const float*)d_in[4];
    const float* rawg  = (const float*)d_in[5];
    const int*   hp    = (const int*)d_in[6];
    const int*   wp    = (const int*)d_in[7];

    int BN = in_sizes[3];            // B*N (1048576 here, % 256 == 0)
    int B  = in_sizes[0] / 16;       // extrinsics: B*1*4*4
    int N  = BN / B;
    int blocks = BN / 256;           // BN % 256 == 0
    int bpb = N / 256;               // blocks per batch

    mono_gaussian_adapter_kernel<<<blocks, 256, 0, stream>>>(
        ext, intr, coord, depth, opac, rawg, hp, wp,
        (float*)d_out, bpb, BN);
}